// Round 7
// baseline (294.183 us; speedup 1.0000x reference)
//
#include <hip/hip_runtime.h>
#include <hip/hip_bf16.h>
#include <stdint.h>

typedef float f32x4 __attribute__((ext_vector_type(4)));
typedef float f32x16 __attribute__((ext_vector_type(16)));
typedef short s16x8 __attribute__((ext_vector_type(8)));
typedef unsigned int u32x2 __attribute__((ext_vector_type(2)));

static __device__ __forceinline__ f32x4 mfma16(s16x8 a, s16x8 b, f32x4 c) {
    return __builtin_amdgcn_mfma_f32_16x16x32_bf16(a, b, c, 0, 0, 0);
}
static __device__ __forceinline__ f32x16 mfma32(s16x8 a, s16x8 b, f32x16 c) {
    return __builtin_amdgcn_mfma_f32_32x32x16_bf16(a, b, c, 0, 0, 0);
}
// async global->LDS, 16B per lane; LDS dest is wave-uniform base + lane*16
static __device__ __forceinline__ void gld16(const void* g, void* l) {
    __builtin_amdgcn_global_load_lds((__attribute__((address_space(1))) void*)(void*)g,
                                     (__attribute__((address_space(3))) void*)l, 16, 0, 0);
}

// ---------------- cos/sin table: [4096][32] ----------------
__global__ __launch_bounds__(256) void k_costab(float* __restrict__ ct, float* __restrict__ st) {
    int i = blockIdx.x * 256 + threadIdx.x;   // 131072 total
    int t = i >> 5, f = i & 31;
    float inv = powf(10000.0f, -(float)f / 32.0f);
    float a = (float)t * inv;
    ct[i] = cosf(a);
    st[i] = sinf(a);
}

// ---------------- fp32 -> bf16 convert + weight concat ----------------
__global__ __launch_bounds__(256) void k_convert(
        const float* __restrict__ x, const float* __restrict__ wq,
        const float* __restrict__ wk, const float* __restrict__ wv,
        const float* __restrict__ wo,
        __hip_bfloat16* __restrict__ xb, __hip_bfloat16* __restrict__ wb,
        __hip_bfloat16* __restrict__ wob) {
    size_t c = (size_t)blockIdx.x * 256 + threadIdx.x;
    if (c >= 1703936) return;
    size_t e = c * 4;
    const float* src;
    __hip_bfloat16* dst;
    if (e < 4194304) { src = x + e; dst = xb + e; }
    else if (e < 5242880) { src = wq + (e - 4194304); dst = wb + (e - 4194304); }
    else if (e < 5505024) { src = wk + (e - 5242880); dst = wb + (e - 4194304); }
    else if (e < 5767168) { src = wv + (e - 5505024); dst = wb + (e - 4194304); }
    else { src = wo + (e - 5767168); dst = wob + (e - 5767168); }
    float4 v = *(const float4*)src;
    ushort4 u;
    u.x = __bfloat16_as_ushort(__float2bfloat16(v.x));
    u.y = __bfloat16_as_ushort(__float2bfloat16(v.y));
    u.z = __bfloat16_as_ushort(__float2bfloat16(v.z));
    u.w = __bfloat16_as_ushort(__float2bfloat16(v.w));
    *(ushort4*)(void*)dst = u;
}

// ---------------- NT GEMM (m97 structure): 128x128 tile, BK=64, global_load_lds ----------------
__global__ __launch_bounds__(256) void k_gemm_bt(
        const __hip_bfloat16* __restrict__ A, const __hip_bfloat16* __restrict__ B,
        float* __restrict__ C, int M, int N, int K) {
    __shared__ __hip_bfloat16 As[128][64];   // 16 KB, linear (gld writes lane*16)
    __shared__ __hip_bfloat16 Bs[128][64];   // 16 KB
    const int tid = threadIdx.x;
    const int wave = tid >> 6, lane = tid & 63;
    const int l15 = lane & 15, l4 = lane >> 4;
    const int wr = (wave >> 1) * 64, wc = (wave & 1) * 64;
    const int row0 = blockIdx.y * 128, col0 = blockIdx.x * 128;
    // staging: wave stages 4 KB of A (rows wave*32..+31) + 4 KB of B, 1KB per gld16
    const int srow = wave * 32 + (lane >> 3);   // +c*8
    const int scol = (lane & 7) * 8;
    f32x4 acc[4][4] = {};
    for (int kb = 0; kb < K; kb += 64) {
        __syncthreads();
#pragma unroll
        for (int c = 0; c < 4; c++) {
            gld16(&A[(size_t)(row0 + srow + c * 8) * K + kb + scol], &As[wave * 32 + c * 8][0]);
            gld16(&B[(size_t)(col0 + srow + c * 8) * K + kb + scol], &Bs[wave * 32 + c * 8][0]);
        }
        __syncthreads();
#pragma unroll
        for (int kk = 0; kk < 2; kk++) {
            s16x8 af[4], bf[4];
#pragma unroll
            for (int m = 0; m < 4; m++)
                af[m] = *(const s16x8*)(const void*)&As[wr + m * 16 + l15][kk * 32 + l4 * 8];
#pragma unroll
            for (int n = 0; n < 4; n++)
                bf[n] = *(const s16x8*)(const void*)&Bs[wc + n * 16 + l15][kk * 32 + l4 * 8];
#pragma unroll
            for (int m = 0; m < 4; m++)
#pragma unroll
                for (int n = 0; n < 4; n++)
                    acc[m][n] = mfma16(af[m], bf[n], acc[m][n]);
        }
    }
#pragma unroll
    for (int m = 0; m < 4; m++)
#pragma unroll
        for (int n = 0; n < 4; n++)
#pragma unroll
            for (int r = 0; r < 4; r++)
                C[(size_t)(row0 + wr + m * 16 + l4 * 4 + r) * N + col0 + wc + n * 16 + l15] = acc[m][n][r];
}

// ---------------- RoPE + scatter (Q pre-scaled by 0.125*log2e for attention) ----------------
__global__ __launch_bounds__(256) void k_rope(
        const float* __restrict__ raw, const float* __restrict__ ct, const float* __restrict__ st,
        __hip_bfloat16* __restrict__ qr, __hip_bfloat16* __restrict__ kr,
        float* __restrict__ outK, float* __restrict__ outV) {
    const float SC = 0.125f * 1.44269504088896340736f;
    int t = blockIdx.x;
    int tid = threadIdx.x;
    const float* r = raw + (size_t)t * 1536;
    for (int p = tid; p < 512; p += 256) {
        int head = p >> 5, f = p & 31;
        float a = r[head * 64 + f], b = r[head * 64 + f + 32];
        float c = ct[t * 32 + f], s = st[t * 32 + f];
        qr[(size_t)t * 1024 + head * 64 + f]      = __float2bfloat16((a * c - b * s) * SC);
        qr[(size_t)t * 1024 + head * 64 + f + 32] = __float2bfloat16((b * c + a * s) * SC);
    }
    if (tid < 128) {
        int kvh = tid >> 5, f = tid & 31;
        float a = r[1024 + kvh * 64 + f], b = r[1024 + kvh * 64 + f + 32];
        float c = ct[t * 32 + f], s = st[t * 32 + f];
        float ra = a * c - b * s, rb = b * c + a * s;
        kr[((size_t)kvh * 4096 + t) * 64 + f]      = __float2bfloat16(ra);
        kr[((size_t)kvh * 4096 + t) * 64 + f + 32] = __float2bfloat16(rb);
#pragma unroll
        for (int rep = 0; rep < 4; rep++) {
            outK[((size_t)(kvh * 4 + rep) * 4096 + t) * 64 + f]      = ra;
            outK[((size_t)(kvh * 4 + rep) * 4096 + t) * 64 + f + 32] = rb;
        }
    }
    {
        int kvh = tid >> 6, d = tid & 63;
        float v = r[1280 + tid];
#pragma unroll
        for (int rep = 0; rep < 4; rep++)
            outV[((size_t)(kvh * 4 + rep) * 4096 + t) * 64 + d] = v;
    }
}

// ---------------- V transpose: raw V cols -> vt[4][64][4096] bf16 ----------------
__global__ __launch_bounds__(256) void k_vtrans(const float* __restrict__ raw,
                                                __hip_bfloat16* __restrict__ vt) {
    int tt = blockIdx.x, kvh = blockIdx.y;
    int tid = threadIdx.x;
    for (int w = tid; w < 512; w += 256) {
        int d = w >> 3, t8 = (w & 7) << 3;
        s16x8 p;
#pragma unroll
        for (int j = 0; j < 8; j++)
            p[j] = __bfloat16_as_short(
                __float2bfloat16(raw[(size_t)(tt * 64 + t8 + j) * 1536 + 1280 + kvh * 64 + d]));
        *(s16x8*)(void*)&vt[((size_t)kvh * 64 + d) * 4096 + tt * 64 + t8] = p;
    }
}

// ---------------- ring attention partials: KV-split flash, 32x32 swapped-operand ----------------
// grid (qt=8, r=7, h=16), 256 thr, forced 4 waves/SIMD. 128 q rows x 1024 keys per block.
// r=0: qb0/k[0,1024); r=2i-1: qb i over dup block i-1; r=2i: qb i over own block i.
// Dup's +ln2 bias applied in k_comb as s+1. V loaded AFTER P-pack (lower reg peak; TLP hides).
__global__ __launch_bounds__(256, 4) void k_attn(
        const __hip_bfloat16* __restrict__ qr, const __hip_bfloat16* __restrict__ kr,
        const __hip_bfloat16* __restrict__ vt, __hip_bfloat16* __restrict__ pO,
        float* __restrict__ ps) {
    const int qt = blockIdx.x, r = blockIdx.y, h = blockIdx.z;
    const int kvh = h >> 2;
    const int tid = threadIdx.x, wave = tid >> 6, lane = tid & 63;
    const int l31 = lane & 31, hi = lane >> 5;
    const int qb = (r + 1) >> 1;
    const int kstart = (r == 0) ? 0 : ((r & 1) ? (qb - 1) * 1024 : qb * 1024);
    const int q0 = qb * 1024 + qt * 128 + wave * 32;
    const __hip_bfloat16* Kh = kr + (size_t)kvh * 4096 * 64;
    const __hip_bfloat16* Vh = vt + (size_t)kvh * 64 * 4096;
    s16x8 qf[4];
#pragma unroll
    for (int dc = 0; dc < 4; dc++)
        qf[dc] = *(const s16x8*)(const void*)
            &qr[(size_t)(q0 + l31) * 1024 + h * 64 + dc * 16 + hi * 8];
    f32x16 oacc[2] = {};                 // rows q=(rr&3)+8*(rr>>2)+4*hi, col d=dh*32+l31
    float mrow = -1e30f, lrow = 0.0f;    // per q=l31 (same in both halves), log2 domain
    for (int t = 0; t < 16; t++) {
        const int k0 = kstart + t * 64;
        // QK^T (swapped): s[ksub][rr] = S[key=ksub*32+(rr&3)+8*(rr>>2)+4*hi][q=l31]
        f32x16 s[2] = {};
#pragma unroll
        for (int dc = 0; dc < 4; dc++) {
#pragma unroll
            for (int ksub = 0; ksub < 2; ksub++) {
                s16x8 kf = *(const s16x8*)(const void*)
                    &Kh[(size_t)(k0 + ksub * 32 + l31) * 64 + dc * 16 + hi * 8];
                s[ksub] = mfma32(kf, qf[dc], s[ksub]);
            }
        }
        // tree max over 32 lane-local scores
        float m[16];
#pragma unroll
        for (int rr = 0; rr < 16; rr++) m[rr] = fmaxf(s[0][rr], s[1][rr]);
#pragma unroll
        for (int d = 8; d >= 1; d >>= 1)
#pragma unroll
            for (int rr = 0; rr < d; rr++) m[rr] = fmaxf(m[rr], m[rr + d]);
        float mx = fmaxf(m[0], __shfl_xor(m[0], 32));
        // defer-max: rescale only when max grew by > 8 (log2 domain)
        if (!__all(mx <= mrow + 8.0f)) {
            float mnew = fmaxf(mrow, mx);
            float alpha = exp2f(mrow - mnew);
            lrow *= alpha;
            mrow = mnew;
#pragma unroll
            for (int rr = 0; rr < 16; rr++) {
                int qrow = (rr & 3) + 8 * (rr >> 2) + 4 * hi;
                float ar = __shfl(alpha, qrow);
                oacc[0][rr] *= ar;
                oacc[1][rr] *= ar;
            }
        }
        // p = exp2(z - m); pack bf16 words; tree-sum
        uint32_t w[2][4][2];
        float pv0[16], pv1[16];
#pragma unroll
        for (int rr = 0; rr < 16; rr++) pv0[rr] = exp2f(s[0][rr] - mrow);
#pragma unroll
        for (int rr = 0; rr < 16; rr++) pv1[rr] = exp2f(s[1][rr] - mrow);
#pragma unroll
        for (int R = 0; R < 4; R++)
#pragma unroll
            for (int u = 0; u < 2; u++) {
                uint32_t lo0 = (uint32_t)__bfloat16_as_ushort(__float2bfloat16(pv0[4 * R + 2 * u]));
                uint32_t hi0 = (uint32_t)__bfloat16_as_ushort(__float2bfloat16(pv0[4 * R + 2 * u + 1]));
                w[0][R][u] = lo0 | (hi0 << 16);
                uint32_t lo1 = (uint32_t)__bfloat16_as_ushort(__float2bfloat16(pv1[4 * R + 2 * u]));
                uint32_t hi1 = (uint32_t)__bfloat16_as_ushort(__float2bfloat16(pv1[4 * R + 2 * u + 1]));
                w[1][R][u] = lo1 | (hi1 << 16);
            }
        float psum[16];
#pragma unroll
        for (int rr = 0; rr < 16; rr++) psum[rr] = pv0[rr] + pv1[rr];
#pragma unroll
        for (int d = 8; d >= 1; d >>= 1)
#pragma unroll
            for (int rr = 0; rr < d; rr++) psum[rr] += psum[rr + d];
        lrow += psum[0] + __shfl_xor(psum[0], 32);
        // V fragments (loaded late: s/K regs dead, lower peak pressure; TLP hides latency)
        s16x8 vf[8];
#pragma unroll
        for (int c = 0; c < 4; c++)
#pragma unroll
            for (int dh = 0; dh < 2; dh++)
                vf[c * 2 + dh] = *(const s16x8*)(const void*)
                    &Vh[(size_t)(dh * 32 + l31) * 4096 + k0 + c * 16 + hi * 8];
        // PV: assemble P A-frags via permlane32_swap (both outputs used)
#pragma unroll
        for (int c = 0; c < 4; c++) {
            const int ksub = c >> 1, cb = c & 1;
            u32x2 e0 = __builtin_amdgcn_permlane32_swap(w[ksub][2 * cb][0], w[ksub][2 * cb + 1][0], false, false);
            u32x2 e1 = __builtin_amdgcn_permlane32_swap(w[ksub][2 * cb][1], w[ksub][2 * cb + 1][1], false, false);
            union { uint32_t u[4]; s16x8 v; } pu;
            pu.u[0] = e0[0];
            pu.u[1] = e1[0];
            pu.u[2] = e0[1];
            pu.u[3] = e1[1];
            oacc[0] = mfma32(pu.v, vf[c * 2 + 0], oacc[0]);
            oacc[1] = mfma32(pu.v, vf[c * 2 + 1], oacc[1]);
        }
    }
    // epilogue: normalized partial O + log-mass s
    const size_t base = ((((size_t)r * 8 + qt) * 16 + h) * 128) + wave * 32;
    float inv = 1.0f / lrow;
#pragma unroll
    for (int rr = 0; rr < 16; rr++) {
        int qrow = (rr & 3) + 8 * (rr >> 2) + 4 * hi;
        float iv = __shfl(inv, qrow);
#pragma unroll
        for (int dh = 0; dh < 2; dh++)
            pO[(base + qrow) * 64 + dh * 32 + l31] = __float2bfloat16(oacc[dh][rr] * iv);
    }
    if (hi == 0) ps[base + l31] = mrow + __log2f(lrow);
}

// ---------------- combine partials -> ao[4096][1024] bf16 ----------------
__global__ __launch_bounds__(256) void k_comb(
        const __hip_bfloat16* __restrict__ pO, const float* __restrict__ ps,
        __hip_bfloat16* __restrict__ ao) {
    int g = blockIdx.x * 256 + threadIdx.x;        // 262144
    int t = g >> 6, rem = g & 63;
    int h = rem >> 2, d0 = (rem & 3) << 4;
    int ib = t >> 10, qt = (t >> 7) & 7, row = t & 127;
    size_t o = (size_t)t * 1024 + h * 64 + d0;
    if (ib == 0) {
        size_t b = ((((size_t)0 * 8 + qt) * 16 + h) * 128 + row) * 64 + d0;
        *(s16x8*)(void*)&ao[o]     = *(const s16x8*)(const void*)&pO[b];
        *(s16x8*)(void*)&ao[o + 8] = *(const s16x8*)(const void*)&pO[b + 8];
    } else {
        int r0 = 2 * ib - 1, r1 = 2 * ib;
        size_t i0 = (((size_t)r0 * 8 + qt) * 16 + h) * 128 + row;
        size_t i1 = (((size_t)r1 * 8 + qt) * 16 + h) * 128 + row;
        float s0 = ps[i0] + 1.0f;      // duplicated block: +ln2 bias == +1 in log2 mass
        float s1 = ps[i1];
        float M = fmaxf(s0, s1);
        float w0 = exp2f(s0 - M), w1 = exp2f(s1 - M);
        float inv = 1.0f / (w0 + w1);
        w0 *= inv; w1 *= inv;
        const ushort* a0 = (const ushort*)(const void*)&pO[i0 * 64 + d0];
        const ushort* a1 = (const ushort*)(const void*)&pO[i1 * 64 + d0];
        ushort outw[16];
#pragma unroll
        for (int j = 0; j < 16; j++) {
            float f0 = __uint_as_float((uint32_t)a0[j] << 16);
            float f1 = __uint_as_float((uint32_t)a1[j] << 16);
            outw[j] = __bfloat16_as_ushort(__float2bfloat16(w0 * f0 + w1 * f1));
        }
        *(ushort4*)(void*)&ao[o]      = *(ushort4*)(void*)&outw[0];
        *(ushort4*)(void*)&ao[o + 4]  = *(ushort4*)(void*)&outw[4];
        *(ushort4*)(void*)&ao[o + 8]  = *(ushort4*)(void*)&outw[8];
        *(ushort4*)(void*)&ao[o + 12] = *(ushort4*)(void*)&outw[12];
    }
}

extern "C" void kernel_launch(void* const* d_in, const int* in_sizes, int n_in,
                              void* d_out, int out_size, void* d_ws, size_t ws_size,
                              hipStream_t stream) {
    const float* x  = (const float*)d_in[0];
    const float* wq = (const float*)d_in[1];
    const float* wk = (const float*)d_in[2];
    const float* wv = (const float*)d_in[3];
    const float* wo = (const float*)d_in[4];
    float* out0 = (float*)d_out;
    float* outK = out0 + 4194304;
    float* outV = out0 + 8388608;
    char* ws = (char*)d_ws;
    __hip_bfloat16* xb  = (__hip_bfloat16*)(ws + 0);          // 8 MB (dead after gemm1)
    __hip_bfloat16* wb  = (__hip_bfloat16*)(ws + 8388608);    // 3 MB (dead after gemm1)
    __hip_bfloat16* wob = (__hip_bfloat16*)(ws + 11534336);   // 2 MB (live till gemm2)
    float* ct           = (float*)(ws + 13631488);            // 512 KB (dead after rope)
    float* st           = (float*)(ws + 14155776);            // 512 KB (dead after rope)
    float* raw          = (float*)(ws + 14680064);            // 25.2 MB (dead after vtrans)
    __hip_bfloat16* pO  = (__hip_bfloat16*)(ws + 14680064);   // 14.68 MB, overlays raw
    float* ps           = (float*)(ws + 29360128);            // 448 KB, overlays raw
    __hip_bfloat16* qr  = (__hip_bfloat16*)(ws + 39845888);   // 8 MB (pre-scaled)
    __hip_bfloat16* kr  = (__hip_bfloat16*)(ws + 48234496);   // 2 MB [4][4096][64]
    __hip_bfloat16* vt  = (__hip_bfloat16*)(ws + 50331648);   // 2 MB [4][64][4096]
    __hip_bfloat16* ao  = (__hip_bfloat16*)(ws + 52428800);   // 8 MB

    hipLaunchKernelGGL(k_costab, dim3(512), dim3(256), 0, stream, ct, st);
    hipLaunchKernelGGL(k_convert, dim3(6656), dim3(256), 0, stream, x, wq, wk, wv, wo, xb, wb, wob);
    hipLaunchKernelGGL(k_gemm_bt, dim3(12, 32), dim3(256), 0, stream, xb, wb, raw, 4096, 1536, 1024);
    hipLaunchKernelGGL(k_rope, dim3(4096), dim3(256), 0, stream, raw, ct, st, qr, kr, outK, outV);
    hipLaunchKernelGGL(k_vtrans, dim3(64, 4), dim3(256), 0, stream, raw, vt);
    hipLaunchKernelGGL(k_attn, dim3(8, 7, 16), dim3(256), 0, stream, qr, kr, vt, pO, ps);
    hipLaunchKernelGGL(k_comb, dim3(1024), dim3(256), 0, stream, pO, ps, ao);
    hipLaunchKernelGGL(k_gemm_bt, dim3(8, 32), dim3(256), 0, stream, ao, wob, out0, 4096, 1024, 1024);
}

// Round 10
// 270.173 us; speedup vs baseline: 1.0889x; 1.0889x over previous
//
#include <hip/hip_runtime.h>
#include <hip/hip_bf16.h>
#include <stdint.h>

typedef float f32x4 __attribute__((ext_vector_type(4)));
typedef float f32x16 __attribute__((ext_vector_type(16)));
typedef short s16x8 __attribute__((ext_vector_type(8)));
typedef unsigned int u32x2 __attribute__((ext_vector_type(2)));

static __device__ __forceinline__ f32x4 mfma16(s16x8 a, s16x8 b, f32x4 c) {
    return __builtin_amdgcn_mfma_f32_16x16x32_bf16(a, b, c, 0, 0, 0);
}
static __device__ __forceinline__ f32x16 mfma32(s16x8 a, s16x8 b, f32x16 c) {
    return __builtin_amdgcn_mfma_f32_32x32x16_bf16(a, b, c, 0, 0, 0);
}
// async global->LDS, 16B per lane; LDS dest is wave-uniform base + lane*16
static __device__ __forceinline__ void gld16(const void* g, void* l) {
    __builtin_amdgcn_global_load_lds((__attribute__((address_space(1))) void*)(void*)g,
                                     (__attribute__((address_space(3))) void*)l, 16, 0, 0);
}
// pack two f32 -> one u32 of 2x bf16 (lo = a, hi = b)
static __device__ __forceinline__ uint32_t cvtpk(float a, float b) {
    uint32_t r;
    asm("v_cvt_pk_bf16_f32 %0, %1, %2" : "=v"(r) : "v"(a), "v"(b));
    return r;
}

// ---------------- cos/sin table: [4096][32] ----------------
__global__ __launch_bounds__(256) void k_costab(float* __restrict__ ct, float* __restrict__ st) {
    int i = blockIdx.x * 256 + threadIdx.x;   // 131072 total
    int t = i >> 5, f = i & 31;
    float inv = powf(10000.0f, -(float)f / 32.0f);
    float a = (float)t * inv;
    ct[i] = cosf(a);
    st[i] = sinf(a);
}

// ---------------- fp32 -> bf16 convert + weight concat ----------------
__global__ __launch_bounds__(256) void k_convert(
        const float* __restrict__ x, const float* __restrict__ wq,
        const float* __restrict__ wk, const float* __restrict__ wv,
        const float* __restrict__ wo,
        __hip_bfloat16* __restrict__ xb, __hip_bfloat16* __restrict__ wb,
        __hip_bfloat16* __restrict__ wob) {
    size_t c = (size_t)blockIdx.x * 256 + threadIdx.x;
    if (c >= 1703936) return;
    size_t e = c * 4;
    const float* src;
    __hip_bfloat16* dst;
    if (e < 4194304) { src = x + e; dst = xb + e; }
    else if (e < 5242880) { src = wq + (e - 4194304); dst = wb + (e - 4194304); }
    else if (e < 5505024) { src = wk + (e - 5242880); dst = wb + (e - 4194304); }
    else if (e < 5767168) { src = wv + (e - 5505024); dst = wb + (e - 4194304); }
    else { src = wo + (e - 5767168); dst = wob + (e - 5767168); }
    float4 v = *(const float4*)src;
    ushort4 u;
    u.x = __bfloat16_as_ushort(__float2bfloat16(v.x));
    u.y = __bfloat16_as_ushort(__float2bfloat16(v.y));
    u.z = __bfloat16_as_ushort(__float2bfloat16(v.z));
    u.w = __bfloat16_as_ushort(__float2bfloat16(v.w));
    *(ushort4*)(void*)dst = u;
}

// ---------------- NT GEMM (m97 structure): 128x128 tile, BK=64, global_load_lds ----------------
__global__ __launch_bounds__(256) void k_gemm_bt(
        const __hip_bfloat16* __restrict__ A, const __hip_bfloat16* __restrict__ B,
        float* __restrict__ C, int M, int N, int K) {
    __shared__ __hip_bfloat16 As[128][64];   // 16 KB, linear (gld writes lane*16)
    __shared__ __hip_bfloat16 Bs[128][64];   // 16 KB
    const int tid = threadIdx.x;
    const int wave = tid >> 6, lane = tid & 63;
    const int l15 = lane & 15, l4 = lane >> 4;
    const int wr = (wave >> 1) * 64, wc = (wave & 1) * 64;
    const int row0 = blockIdx.y * 128, col0 = blockIdx.x * 128;
    const int srow = wave * 32 + (lane >> 3);   // +c*8
    const int scol = (lane & 7) * 8;
    f32x4 acc[4][4] = {};
    for (int kb = 0; kb < K; kb += 64) {
        __syncthreads();
#pragma unroll
        for (int c = 0; c < 4; c++) {
            gld16(&A[(size_t)(row0 + srow + c * 8) * K + kb + scol], &As[wave * 32 + c * 8][0]);
            gld16(&B[(size_t)(col0 + srow + c * 8) * K + kb + scol], &Bs[wave * 32 + c * 8][0]);
        }
        __syncthreads();
#pragma unroll
        for (int kk = 0; kk < 2; kk++) {
            s16x8 af[4], bf[4];
#pragma unroll
            for (int m = 0; m < 4; m++)
                af[m] = *(const s16x8*)(const void*)&As[wr + m * 16 + l15][kk * 32 + l4 * 8];
#pragma unroll
            for (int n = 0; n < 4; n++)
                bf[n] = *(const s16x8*)(const void*)&Bs[wc + n * 16 + l15][kk * 32 + l4 * 8];
#pragma unroll
            for (int m = 0; m < 4; m++)
#pragma unroll
                for (int n = 0; n < 4; n++)
                    acc[m][n] = mfma16(af[m], bf[n], acc[m][n]);
        }
    }
#pragma unroll
    for (int m = 0; m < 4; m++)
#pragma unroll
        for (int n = 0; n < 4; n++)
#pragma unroll
            for (int r = 0; r < 4; r++)
                C[(size_t)(row0 + wr + m * 16 + l4 * 4 + r) * N + col0 + wc + n * 16 + l15] = acc[m][n][r];
}

// ---------------- RoPE + scatter (Q pre-scaled by 0.125*log2e for attention) ----------------
__global__ __launch_bounds__(256) void k_rope(
        const float* __restrict__ raw, const float* __restrict__ ct, const float* __restrict__ st,
        __hip_bfloat16* __restrict__ qr, __hip_bfloat16* __restrict__ kr,
        float* __restrict__ outK, float* __restrict__ outV) {
    const float SC = 0.125f * 1.44269504088896340736f;
    int t = blockIdx.x;
    int tid = threadIdx.x;
    const float* r = raw + (size_t)t * 1536;
    for (int p = tid; p < 512; p += 256) {
        int head = p >> 5, f = p & 31;
        float a = r[head * 64 + f], b = r[head * 64 + f + 32];
        float c = ct[t * 32 + f], s = st[t * 32 + f];
        qr[(size_t)t * 1024 + head * 64 + f]      = __float2bfloat16((a * c - b * s) * SC);
        qr[(size_t)t * 1024 + head * 64 + f + 32] = __float2bfloat16((b * c + a * s) * SC);
    }
    if (tid < 128) {
        int kvh = tid >> 5, f = tid & 31;
        float a = r[1024 + kvh * 64 + f], b = r[1024 + kvh * 64 + f + 32];
        float c = ct[t * 32 + f], s = st[t * 32 + f];
        float ra = a * c - b * s, rb = b * c + a * s;
        kr[((size_t)kvh * 4096 + t) * 64 + f]      = __float2bfloat16(ra);
        kr[((size_t)kvh * 4096 + t) * 64 + f + 32] = __float2bfloat16(rb);
#pragma unroll
        for (int rep = 0; rep < 4; rep++) {
            outK[((size_t)(kvh * 4 + rep) * 4096 + t) * 64 + f]      = ra;
            outK[((size_t)(kvh * 4 + rep) * 4096 + t) * 64 + f + 32] = rb;
        }
    }
    {
        int kvh = tid >> 6, d = tid & 63;
        float v = r[1280 + tid];
#pragma unroll
        for (int rep = 0; rep < 4; rep++)
            outV[((size_t)(kvh * 4 + rep) * 4096 + t) * 64 + d] = v;
    }
}

// ---------------- V transpose (LDS-tiled): raw V -> vt[4][64][4096] bf16 ----------------
// block (tt, kvh): 64 t-rows x 64 d. Coalesced 256B global reads, 128B writes.
__global__ __launch_bounds__(256) void k_vtrans(const float* __restrict__ raw,
                                                __hip_bfloat16* __restrict__ vt) {
    __shared__ float T[64][65];
    const int tt = blockIdx.x, kvh = blockIdx.y;
    const int tid = threadIdx.x;
    const int r = tid >> 2, c0 = (tid & 3) << 4;
    const float* src = raw + (size_t)(tt * 64 + r) * 1536 + 1280 + kvh * 64 + c0;
#pragma unroll
    for (int j = 0; j < 4; j++) {
        float4 v = *(const float4*)(src + j * 4);
        T[r][c0 + j * 4 + 0] = v.x;
        T[r][c0 + j * 4 + 1] = v.y;
        T[r][c0 + j * 4 + 2] = v.z;
        T[r][c0 + j * 4 + 3] = v.w;
    }
    __syncthreads();
    const int d = tid >> 2, t0 = (tid & 3) << 4;
    ushort u[16];
#pragma unroll
    for (int j = 0; j < 16; j++)
        u[j] = __bfloat16_as_ushort(__float2bfloat16(T[t0 + j][d]));
    __hip_bfloat16* dst = vt + ((size_t)kvh * 64 + d) * 4096 + tt * 64 + t0;
    *(ushort4*)(void*)&dst[0]  = *(ushort4*)(void*)&u[0];
    *(ushort4*)(void*)&dst[4]  = *(ushort4*)(void*)&u[4];
    *(ushort4*)(void*)&dst[8]  = *(ushort4*)(void*)&u[8];
    *(ushort4*)(void*)&dst[12] = *(ushort4*)(void*)&u[12];
}

// ---------------- ring attention: 32x32 swapped-operand, P in registers ----------------
// grid (qt=8, ib=4, h=16), 256 thr. Wave owns 32 q rows; kv tiles of 64 keys.
// S^T = mfma32(K, Q); softmax lane-local + 1 shfl_xor(32); P pack via v_cvt_pk_bf16_f32;
// A-frag exchange via permlane32_swap; defer-max THR=8 (log2 domain).
__global__ __launch_bounds__(256) void k_attn(
        const __hip_bfloat16* __restrict__ qr, const __hip_bfloat16* __restrict__ kr,
        const __hip_bfloat16* __restrict__ vt, __hip_bfloat16* __restrict__ ao) {
    const int qt = blockIdx.x, ib = blockIdx.y, h = blockIdx.z;
    const int kvh = h >> 2;
    const int tid = threadIdx.x, wave = tid >> 6, lane = tid & 63;
    const int l31 = lane & 31, hi = lane >> 5;
    const int q0 = ib * 1024 + qt * 128 + wave * 32;
    const __hip_bfloat16* Kh = kr + (size_t)kvh * 4096 * 64;
    const __hip_bfloat16* Vh = vt + (size_t)kvh * 64 * 4096;
    s16x8 qf[4];
#pragma unroll
    for (int dc = 0; dc < 4; dc++)
        qf[dc] = *(const s16x8*)(const void*)
            &qr[(size_t)(q0 + l31) * 1024 + h * 64 + dc * 16 + hi * 8];
    f32x16 oacc[2] = {};                 // rows q=(rr&3)+8*(rr>>2)+4*hi, col d=dh*32+l31
    float mrow = -1e30f, lrow = 0.0f;    // per q=l31 (same in both halves), log2 domain
    const int kstart = (ib == 0) ? 0 : (ib - 1) * 1024;
    const int ntiles = (ib == 0) ? 16 : 32;
    const int nbias  = (ib == 0) ? 0 : 16;   // duplicated block => +1.0 in log2 domain
    for (int t = 0; t < ntiles; t++) {
        const int k0 = kstart + t * 64;
        // QK^T (swapped): s[ksub][rr] = S[key=ksub*32+(rr&3)+8*(rr>>2)+4*hi][q=l31]
        f32x16 s[2] = {};
#pragma unroll
        for (int dc = 0; dc < 4; dc++) {
#pragma unroll
            for (int ksub = 0; ksub < 2; ksub++) {
                s16x8 kf = *(const s16x8*)(const void*)
                    &Kh[(size_t)(k0 + ksub * 32 + l31) * 64 + dc * 16 + hi * 8];
                s[ksub] = mfma32(kf, qf[dc], s[ksub]);
            }
        }
        // V fragments (independent of P: latency overlaps softmax)
        s16x8 vf[8];
#pragma unroll
        for (int c = 0; c < 4; c++)
#pragma unroll
            for (int dh = 0; dh < 2; dh++)
                vf[c * 2 + dh] = *(const s16x8*)(const void*)
                    &Vh[(size_t)(dh * 32 + l31) * 4096 + k0 + c * 16 + hi * 8];
        const float bias = (t < nbias) ? 1.0f : 0.0f;
        // tree max over 32 lane-local scores
        float m[16];
#pragma unroll
        for (int rr = 0; rr < 16; rr++) m[rr] = fmaxf(s[0][rr], s[1][rr]);
#pragma unroll
        for (int d = 8; d >= 1; d >>= 1)
#pragma unroll
            for (int rr = 0; rr < d; rr++) m[rr] = fmaxf(m[rr], m[rr + d]);
        float mx = fmaxf(m[0], __shfl_xor(m[0], 32)) + bias;
        // defer-max: rescale only when max grew by > 8 (log2 domain)
        if (!__all(mx <= mrow + 8.0f)) {
            float mnew = fmaxf(mrow, mx);
            float alpha = exp2f(mrow - mnew);
            lrow *= alpha;
            mrow = mnew;
#pragma unroll
            for (int rr = 0; rr < 16; rr++) {
                int qrow = (rr & 3) + 8 * (rr >> 2) + 4 * hi;
                float ar = __shfl(alpha, qrow);
                oacc[0][rr] *= ar;
                oacc[1][rr] *= ar;
            }
        }
        const float mb = mrow - bias;
        // p = exp2(z - mb); pack via v_cvt_pk_bf16_f32; tree-sum
        float pv0[16], pv1[16];
#pragma unroll
        for (int rr = 0; rr < 16; rr++) pv0[rr] = exp2f(s[0][rr] - mb);
#pragma unroll
        for (int rr = 0; rr < 16; rr++) pv1[rr] = exp2f(s[1][rr] - mb);
        uint32_t w[2][4][2];
#pragma unroll
        for (int R = 0; R < 4; R++)
#pragma unroll
            for (int u = 0; u < 2; u++) {
                w[0][R][u] = cvtpk(pv0[4 * R + 2 * u], pv0[4 * R + 2 * u + 1]);
                w[1][R][u] = cvtpk(pv1[4 * R + 2 * u], pv1[4 * R + 2 * u + 1]);
            }
        float psum[16];
#pragma unroll
        for (int rr = 0; rr < 16; rr++) psum[rr] = pv0[rr] + pv1[rr];
#pragma unroll
        for (int d = 8; d >= 1; d >>= 1)
#pragma unroll
            for (int rr = 0; rr < d; rr++) psum[rr] += psum[rr + d];
        lrow += psum[0] + __shfl_xor(psum[0], 32);
        // PV: assemble P A-frags via permlane32_swap (both outputs used)
#pragma unroll
        for (int c = 0; c < 4; c++) {
            const int ksub = c >> 1, cb = c & 1;
            u32x2 e0 = __builtin_amdgcn_permlane32_swap(w[ksub][2 * cb][0], w[ksub][2 * cb + 1][0], false, false);
            u32x2 e1 = __builtin_amdgcn_permlane32_swap(w[ksub][2 * cb][1], w[ksub][2 * cb + 1][1], false, false);
            union { uint32_t u[4]; s16x8 v; } pu;
            pu.u[0] = e0[0];
            pu.u[1] = e1[0];
            pu.u[2] = e0[1];
            pu.u[3] = e1[1];
            oacc[0] = mfma32(pu.v, vf[c * 2 + 0], oacc[0]);
            oacc[1] = mfma32(pu.v, vf[c * 2 + 1], oacc[1]);
        }
    }
    // epilogue: normalize rows and store
    float inv = 1.0f / lrow;
#pragma unroll
    for (int rr = 0; rr < 16; rr++) {
        int qrow = (rr & 3) + 8 * (rr >> 2) + 4 * hi;
        float iv = __shfl(inv, qrow);
#pragma unroll
        for (int dh = 0; dh < 2; dh++)
            ao[(size_t)(q0 + qrow) * 1024 + h * 64 + dh * 32 + l31] =
                __float2bfloat16(oacc[dh][rr] * iv);
    }
}

extern "C" void kernel_launch(void* const* d_in, const int* in_sizes, int n_in,
                              void* d_out, int out_size, void* d_ws, size_t ws_size,
                              hipStream_t stream) {
    const float* x  = (const float*)d_in[0];
    const float* wq = (const float*)d_in[1];
    const float* wk = (const float*)d_in[2];
    const float* wv = (const float*)d_in[3];
    const float* wo = (const float*)d_in[4];
    float* out0 = (float*)d_out;
    float* outK = out0 + 4194304;
    float* outV = out0 + 8388608;
    char* ws = (char*)d_ws;
    __hip_bfloat16* xb  = (__hip_bfloat16*)(ws + 0);          // 8 MB (dead after gemm1)
    __hip_bfloat16* wb  = (__hip_bfloat16*)(ws + 8388608);    // 3 MB (dead after gemm1)
    __hip_bfloat16* wob = (__hip_bfloat16*)(ws + 11534336);   // 2 MB (live till gemm2)
    float* ct           = (float*)(ws + 13631488);            // 512 KB (dead after rope)
    float* st           = (float*)(ws + 14155776);            // 512 KB (dead after rope)
    float* raw          = (float*)(ws + 14680064);            // 25.2 MB (dead after vtrans)
    __hip_bfloat16* qr  = (__hip_bfloat16*)(ws + 39845888);   // 8 MB (pre-scaled)
    __hip_bfloat16* kr  = (__hip_bfloat16*)(ws + 48234496);   // 2 MB [4][4096][64]
    __hip_bfloat16* vt  = (__hip_bfloat16*)(ws + 50331648);   // 2 MB [4][64][4096]
    __hip_bfloat16* ao  = (__hip_bfloat16*)(ws + 52428800);   // 8 MB

    hipLaunchKernelGGL(k_costab, dim3(512), dim3(256), 0, stream, ct, st);
    hipLaunchKernelGGL(k_convert, dim3(6656), dim3(256), 0, stream, x, wq, wk, wv, wo, xb, wb, wob);
    hipLaunchKernelGGL(k_gemm_bt, dim3(12, 32), dim3(256), 0, stream, xb, wb, raw, 4096, 1536, 1024);
    hipLaunchKernelGGL(k_rope, dim3(4096), dim3(256), 0, stream, raw, ct, st, qr, kr, outK, outV);
    hipLaunchKernelGGL(k_vtrans, dim3(64, 4), dim3(256), 0, stream, raw, vt);
    hipLaunchKernelGGL(k_attn, dim3(8, 4, 16), dim3(256), 0, stream, qr, kr, vt, ao);
    hipLaunchKernelGGL(k_gemm_bt, dim3(8, 32), dim3(256), 0, stream, ao, wob, out0, 4096, 1024, 1024);
}

// Round 11
// 225.079 us; speedup vs baseline: 1.3070x; 1.2003x over previous
//
#include <hip/hip_runtime.h>
#include <hip/hip_bf16.h>
#include <stdint.h>

typedef float f32x4 __attribute__((ext_vector_type(4)));
typedef float f32x16 __attribute__((ext_vector_type(16)));
typedef short s16x8 __attribute__((ext_vector_type(8)));
typedef unsigned int u32x2 __attribute__((ext_vector_type(2)));

static __device__ __forceinline__ f32x4 mfma16(s16x8 a, s16x8 b, f32x4 c) {
    return __builtin_amdgcn_mfma_f32_16x16x32_bf16(a, b, c, 0, 0, 0);
}
static __device__ __forceinline__ f32x16 mfma32(s16x8 a, s16x8 b, f32x16 c) {
    return __builtin_amdgcn_mfma_f32_32x32x16_bf16(a, b, c, 0, 0, 0);
}
// async global->LDS, 16B per lane; LDS dest is wave-uniform base + lane*16
static __device__ __forceinline__ void gld16(const void* g, void* l) {
    __builtin_amdgcn_global_load_lds((__attribute__((address_space(1))) void*)(void*)g,
                                     (__attribute__((address_space(3))) void*)l, 16, 0, 0);
}
// pack two f32 -> one u32 of 2x bf16 (lo = a, hi = b)
static __device__ __forceinline__ uint32_t cvtpk(float a, float b) {
    uint32_t r;
    asm("v_cvt_pk_bf16_f32 %0, %1, %2" : "=v"(r) : "v"(a), "v"(b));
    return r;
}

// ---------------- cos/sin table: [4096][32] ----------------
__global__ __launch_bounds__(256) void k_costab(float* __restrict__ ct, float* __restrict__ st) {
    int i = blockIdx.x * 256 + threadIdx.x;   // 131072 total
    int t = i >> 5, f = i & 31;
    float inv = powf(10000.0f, -(float)f / 32.0f);
    float a = (float)t * inv;
    ct[i] = cosf(a);
    st[i] = sinf(a);
}

// ---------------- fp32 -> bf16 convert + weight concat ----------------
__global__ __launch_bounds__(256) void k_convert(
        const float* __restrict__ x, const float* __restrict__ wq,
        const float* __restrict__ wk, const float* __restrict__ wv,
        const float* __restrict__ wo,
        __hip_bfloat16* __restrict__ xb, __hip_bfloat16* __restrict__ wb,
        __hip_bfloat16* __restrict__ wob) {
    size_t c = (size_t)blockIdx.x * 256 + threadIdx.x;
    if (c >= 1703936) return;
    size_t e = c * 4;
    const float* src;
    __hip_bfloat16* dst;
    if (e < 4194304) { src = x + e; dst = xb + e; }
    else if (e < 5242880) { src = wq + (e - 4194304); dst = wb + (e - 4194304); }
    else if (e < 5505024) { src = wk + (e - 5242880); dst = wb + (e - 4194304); }
    else if (e < 5767168) { src = wv + (e - 5505024); dst = wb + (e - 4194304); }
    else { src = wo + (e - 5767168); dst = wob + (e - 5767168); }
    float4 v = *(const float4*)src;
    ushort4 u;
    u.x = __bfloat16_as_ushort(__float2bfloat16(v.x));
    u.y = __bfloat16_as_ushort(__float2bfloat16(v.y));
    u.z = __bfloat16_as_ushort(__float2bfloat16(v.z));
    u.w = __bfloat16_as_ushort(__float2bfloat16(v.w));
    *(ushort4*)(void*)dst = u;
}

// ---------------- NT GEMM (m97 structure): 128x128 tile, BK=64, global_load_lds ----------------
__global__ __launch_bounds__(256) void k_gemm_bt(
        const __hip_bfloat16* __restrict__ A, const __hip_bfloat16* __restrict__ B,
        float* __restrict__ C, int M, int N, int K) {
    __shared__ __hip_bfloat16 As[128][64];   // 16 KB, linear (gld writes lane*16)
    __shared__ __hip_bfloat16 Bs[128][64];   // 16 KB
    const int tid = threadIdx.x;
    const int wave = tid >> 6, lane = tid & 63;
    const int l15 = lane & 15, l4 = lane >> 4;
    const int wr = (wave >> 1) * 64, wc = (wave & 1) * 64;
    const int row0 = blockIdx.y * 128, col0 = blockIdx.x * 128;
    const int srow = wave * 32 + (lane >> 3);   // +c*8
    const int scol = (lane & 7) * 8;
    f32x4 acc[4][4] = {};
    for (int kb = 0; kb < K; kb += 64) {
        __syncthreads();
#pragma unroll
        for (int c = 0; c < 4; c++) {
            gld16(&A[(size_t)(row0 + srow + c * 8) * K + kb + scol], &As[wave * 32 + c * 8][0]);
            gld16(&B[(size_t)(col0 + srow + c * 8) * K + kb + scol], &Bs[wave * 32 + c * 8][0]);
        }
        __syncthreads();
#pragma unroll
        for (int kk = 0; kk < 2; kk++) {
            s16x8 af[4], bf[4];
#pragma unroll
            for (int m = 0; m < 4; m++)
                af[m] = *(const s16x8*)(const void*)&As[wr + m * 16 + l15][kk * 32 + l4 * 8];
#pragma unroll
            for (int n = 0; n < 4; n++)
                bf[n] = *(const s16x8*)(const void*)&Bs[wc + n * 16 + l15][kk * 32 + l4 * 8];
#pragma unroll
            for (int m = 0; m < 4; m++)
#pragma unroll
                for (int n = 0; n < 4; n++)
                    acc[m][n] = mfma16(af[m], bf[n], acc[m][n]);
        }
    }
#pragma unroll
    for (int m = 0; m < 4; m++)
#pragma unroll
        for (int n = 0; n < 4; n++)
#pragma unroll
            for (int r = 0; r < 4; r++)
                C[(size_t)(row0 + wr + m * 16 + l4 * 4 + r) * N + col0 + wc + n * 16 + l15] = acc[m][n][r];
}

// ---------------- RoPE + scatter (Q pre-scaled; K written fragment-packed) ----------------
// krp chunk layout: [kvh][kblk=t/32][dc] of 512 bf16; slot (hi*32 + t%32)*8 + j holds
// K[t][dc*16 + hi*8 + j]  => wave load @ lane*16B is fully coalesced in k_attn.
__global__ __launch_bounds__(256) void k_rope(
        const float* __restrict__ raw, const float* __restrict__ ct, const float* __restrict__ st,
        __hip_bfloat16* __restrict__ qr, __hip_bfloat16* __restrict__ krp,
        float* __restrict__ outK, float* __restrict__ outV) {
    const float SC = 0.125f * 1.44269504088896340736f;
    int t = blockIdx.x;
    int tid = threadIdx.x;
    const float* r = raw + (size_t)t * 1536;
    for (int p = tid; p < 512; p += 256) {
        int head = p >> 5, f = p & 31;
        float a = r[head * 64 + f], b = r[head * 64 + f + 32];
        float c = ct[t * 32 + f], s = st[t * 32 + f];
        qr[(size_t)t * 1024 + head * 64 + f]      = __float2bfloat16((a * c - b * s) * SC);
        qr[(size_t)t * 1024 + head * 64 + f + 32] = __float2bfloat16((b * c + a * s) * SC);
    }
    if (tid < 128) {
        int kvh = tid >> 5, f = tid & 31;
        float a = r[1024 + kvh * 64 + f], b = r[1024 + kvh * 64 + f + 32];
        float c = ct[t * 32 + f], s = st[t * 32 + f];
        float ra = a * c - b * s, rb = b * c + a * s;
        int kblk = t >> 5, l31r = t & 31;
        int dc = f >> 4, hif = (f >> 3) & 1, jf = f & 7;
        size_t slot = (size_t)(hif * 32 + l31r) * 8 + jf;
        krp[(((size_t)kvh * 128 + kblk) * 4 + dc) * 512 + slot]       = __float2bfloat16(ra);
        krp[(((size_t)kvh * 128 + kblk) * 4 + (dc + 2)) * 512 + slot] = __float2bfloat16(rb);
#pragma unroll
        for (int rep = 0; rep < 4; rep++) {
            outK[((size_t)(kvh * 4 + rep) * 4096 + t) * 64 + f]      = ra;
            outK[((size_t)(kvh * 4 + rep) * 4096 + t) * 64 + f + 32] = rb;
        }
    }
    {
        int kvh = tid >> 6, d = tid & 63;
        float v = r[1280 + tid];
#pragma unroll
        for (int rep = 0; rep < 4; rep++)
            outV[((size_t)(kvh * 4 + rep) * 4096 + t) * 64 + d] = v;
    }
}

// ---------------- V transpose -> fragment-packed vtp ----------------
// vtp chunk layout: [kvh][ktile=k/64][c][dh] of 512 bf16; slot lane*8+j holds
// V[ktile*64 + c*16 + (lane>>5)*8 + j][kvh*64 + dh*32 + (lane&31)].
__global__ __launch_bounds__(256) void k_vtrans(const float* __restrict__ raw,
                                                __hip_bfloat16* __restrict__ vtp) {
    __shared__ float T[64][65];
    const int tt = blockIdx.x, kvh = blockIdx.y;
    const int tid = threadIdx.x;
    const int r = tid >> 2, c0 = (tid & 3) << 4;
    const float* src = raw + (size_t)(tt * 64 + r) * 1536 + 1280 + kvh * 64 + c0;
#pragma unroll
    for (int j = 0; j < 4; j++) {
        float4 v = *(const float4*)(src + j * 4);
        T[r][c0 + j * 4 + 0] = v.x;
        T[r][c0 + j * 4 + 1] = v.y;
        T[r][c0 + j * 4 + 2] = v.z;
        T[r][c0 + j * 4 + 3] = v.w;
    }
    __syncthreads();
#pragma unroll
    for (int i = 0; i < 2; i++) {
        int s = tid + i * 256;                   // 0..511 = (c,dh,lane)
        int lane = s & 63, dh = (s >> 6) & 1, c = s >> 7;
        int hi = lane >> 5, l31 = lane & 31;
        ushort u[8];
#pragma unroll
        for (int j = 0; j < 8; j++)
            u[j] = __bfloat16_as_ushort(__float2bfloat16(T[c * 16 + hi * 8 + j][dh * 32 + l31]));
        *(s16x8*)(void*)&vtp[(((size_t)(kvh * 64 + tt)) * 8 + c * 2 + dh) * 512 + lane * 8] =
            *(s16x8*)(void*)u;
    }
}

// ---------------- ring attention: 32x32 swapped-operand, fragment-packed K/V ----------------
// grid (qt=8, ib=4, h=16), 256 thr. Wave owns 32 q rows; kv tiles of 64 keys.
// All K/V loads are contiguous 1KB wave-loads (lane*16B) from krp/vtp.
__global__ __launch_bounds__(256) void k_attn(
        const __hip_bfloat16* __restrict__ qr, const __hip_bfloat16* __restrict__ krp,
        const __hip_bfloat16* __restrict__ vtp, __hip_bfloat16* __restrict__ ao) {
    const int qt = blockIdx.x, ib = blockIdx.y, h = blockIdx.z;
    const int kvh = h >> 2;
    const int tid = threadIdx.x, wave = tid >> 6, lane = tid & 63;
    const int l31 = lane & 31, hi = lane >> 5;
    const int q0 = ib * 1024 + qt * 128 + wave * 32;
    const __hip_bfloat16* Kp = krp + (size_t)kvh * 262144;   // 128 kblk x 4 dc x 512
    const __hip_bfloat16* Vp = vtp + (size_t)kvh * 262144;   // 64 ktile x 8 (c,dh) x 512
    s16x8 qf[4];
#pragma unroll
    for (int dc = 0; dc < 4; dc++)
        qf[dc] = *(const s16x8*)(const void*)
            &qr[(size_t)(q0 + l31) * 1024 + h * 64 + dc * 16 + hi * 8];
    f32x16 oacc[2] = {};                 // rows q=(rr&3)+8*(rr>>2)+4*hi, col d=dh*32+l31
    float mrow = -1e30f, lrow = 0.0f;    // per q=l31 (same in both halves), log2 domain
    const int kstart = (ib == 0) ? 0 : (ib - 1) * 1024;
    const int ntiles = (ib == 0) ? 16 : 32;
    const int nbias  = (ib == 0) ? 0 : 16;   // duplicated block => +1.0 in log2 domain
    for (int t = 0; t < ntiles; t++) {
        const int k0 = kstart + t * 64;
        const int kblk = k0 >> 5, ktile = k0 >> 6;
        // QK^T (swapped): s[ksub][rr] = S[key=ksub*32+(rr&3)+8*(rr>>2)+4*hi][q=l31]
        f32x16 s[2] = {};
#pragma unroll
        for (int dc = 0; dc < 4; dc++) {
#pragma unroll
            for (int ksub = 0; ksub < 2; ksub++) {
                s16x8 kf = *(const s16x8*)(const void*)
                    &Kp[(((size_t)(kblk + ksub)) * 4 + dc) * 512 + lane * 8];
                s[ksub] = mfma32(kf, qf[dc], s[ksub]);
            }
        }
        // V fragments (independent of P: latency overlaps softmax)
        s16x8 vf[8];
#pragma unroll
        for (int c = 0; c < 4; c++)
#pragma unroll
            for (int dh = 0; dh < 2; dh++)
                vf[c * 2 + dh] = *(const s16x8*)(const void*)
                    &Vp[((size_t)ktile * 8 + c * 2 + dh) * 512 + lane * 8];
        const float bias = (t < nbias) ? 1.0f : 0.0f;
        // tree max over 32 lane-local scores
        float m[16];
#pragma unroll
        for (int rr = 0; rr < 16; rr++) m[rr] = fmaxf(s[0][rr], s[1][rr]);
#pragma unroll
        for (int d = 8; d >= 1; d >>= 1)
#pragma unroll
            for (int rr = 0; rr < d; rr++) m[rr] = fmaxf(m[rr], m[rr + d]);
        float mx = fmaxf(m[0], __shfl_xor(m[0], 32)) + bias;
        // defer-max: rescale only when max grew by > 8 (log2 domain)
        if (!__all(mx <= mrow + 8.0f)) {
            float mnew = fmaxf(mrow, mx);
            float alpha = exp2f(mrow - mnew);
            lrow *= alpha;
            mrow = mnew;
#pragma unroll
            for (int rr = 0; rr < 16; rr++) {
                int qrow = (rr & 3) + 8 * (rr >> 2) + 4 * hi;
                float ar = __shfl(alpha, qrow);
                oacc[0][rr] *= ar;
                oacc[1][rr] *= ar;
            }
        }
        const float mb = mrow - bias;
        // p = exp2(z - mb); pack via v_cvt_pk_bf16_f32; tree-sum
        float pv0[16], pv1[16];
#pragma unroll
        for (int rr = 0; rr < 16; rr++) pv0[rr] = exp2f(s[0][rr] - mb);
#pragma unroll
        for (int rr = 0; rr < 16; rr++) pv1[rr] = exp2f(s[1][rr] - mb);
        uint32_t w[2][4][2];
#pragma unroll
        for (int R = 0; R < 4; R++)
#pragma unroll
            for (int u = 0; u < 2; u++) {
                w[0][R][u] = cvtpk(pv0[4 * R + 2 * u], pv0[4 * R + 2 * u + 1]);
                w[1][R][u] = cvtpk(pv1[4 * R + 2 * u], pv1[4 * R + 2 * u + 1]);
            }
        float psum[16];
#pragma unroll
        for (int rr = 0; rr < 16; rr++) psum[rr] = pv0[rr] + pv1[rr];
#pragma unroll
        for (int d = 8; d >= 1; d >>= 1)
#pragma unroll
            for (int rr = 0; rr < d; rr++) psum[rr] += psum[rr + d];
        lrow += psum[0] + __shfl_xor(psum[0], 32);
        // PV: assemble P A-frags via permlane32_swap (both outputs used)
#pragma unroll
        for (int c = 0; c < 4; c++) {
            const int ksub = c >> 1, cb = c & 1;
            u32x2 e0 = __builtin_amdgcn_permlane32_swap(w[ksub][2 * cb][0], w[ksub][2 * cb + 1][0], false, false);
            u32x2 e1 = __builtin_amdgcn_permlane32_swap(w[ksub][2 * cb][1], w[ksub][2 * cb + 1][1], false, false);
            union { uint32_t u[4]; s16x8 v; } pu;
            pu.u[0] = e0[0];
            pu.u[1] = e1[0];
            pu.u[2] = e0[1];
            pu.u[3] = e1[1];
            oacc[0] = mfma32(pu.v, vf[c * 2 + 0], oacc[0]);
            oacc[1] = mfma32(pu.v, vf[c * 2 + 1], oacc[1]);
        }
    }
    // epilogue: normalize rows and store
    float inv = 1.0f / lrow;
#pragma unroll
    for (int rr = 0; rr < 16; rr++) {
        int qrow = (rr & 3) + 8 * (rr >> 2) + 4 * hi;
        float iv = __shfl(inv, qrow);
#pragma unroll
        for (int dh = 0; dh < 2; dh++)
            ao[(size_t)(q0 + qrow) * 1024 + h * 64 + dh * 32 + l31] =
                __float2bfloat16(oacc[dh][rr] * iv);
    }
}

extern "C" void kernel_launch(void* const* d_in, const int* in_sizes, int n_in,
                              void* d_out, int out_size, void* d_ws, size_t ws_size,
                              hipStream_t stream) {
    const float* x  = (const float*)d_in[0];
    const float* wq = (const float*)d_in[1];
    const float* wk = (const float*)d_in[2];
    const float* wv = (const float*)d_in[3];
    const float* wo = (const float*)d_in[4];
    float* out0 = (float*)d_out;
    float* outK = out0 + 4194304;
    float* outV = out0 + 8388608;
    char* ws = (char*)d_ws;
    __hip_bfloat16* xb  = (__hip_bfloat16*)(ws + 0);          // 8 MB (dead after gemm1)
    __hip_bfloat16* wb  = (__hip_bfloat16*)(ws + 8388608);    // 3 MB (dead after gemm1)
    __hip_bfloat16* wob = (__hip_bfloat16*)(ws + 11534336);   // 2 MB (live till gemm2)
    float* ct           = (float*)(ws + 13631488);            // 512 KB (dead after rope)
    float* st           = (float*)(ws + 14155776);            // 512 KB (dead after rope)
    float* raw          = (float*)(ws + 14680064);            // 25.2 MB (dead after vtrans)
    __hip_bfloat16* qr  = (__hip_bfloat16*)(ws + 39845888);   // 8 MB (pre-scaled)
    __hip_bfloat16* krp = (__hip_bfloat16*)(ws + 48234496);   // 2 MB fragment-packed K
    __hip_bfloat16* vtp = (__hip_bfloat16*)(ws + 50331648);   // 2 MB fragment-packed V^T
    __hip_bfloat16* ao  = (__hip_bfloat16*)(ws + 52428800);   // 8 MB

    hipLaunchKernelGGL(k_costab, dim3(512), dim3(256), 0, stream, ct, st);
    hipLaunchKernelGGL(k_convert, dim3(6656), dim3(256), 0, stream, x, wq, wk, wv, wo, xb, wb, wob);
    hipLaunchKernelGGL(k_gemm_bt, dim3(12, 32), dim3(256), 0, stream, xb, wb, raw, 4096, 1536, 1024);
    hipLaunchKernelGGL(k_rope, dim3(4096), dim3(256), 0, stream, raw, ct, st, qr, krp, outK, outV);
    hipLaunchKernelGGL(k_vtrans, dim3(64, 4), dim3(256), 0, stream, raw, vtp);
    hipLaunchKernelGGL(k_attn, dim3(8, 4, 16), dim3(256), 0, stream, qr, krp, vtp, ao);
    hipLaunchKernelGGL(k_gemm_bt, dim3(8, 32), dim3(256), 0, stream, ao, wob, out0, 4096, 1024, 1024);
}